// Round 1
// baseline (143.224 us; speedup 1.0000x reference)
//
#include <hip/hip_runtime.h>
#include <hip/hip_bf16.h>
#include <math.h>

#define B_   128
#define LQ_  64
#define LD_  512
#define E_   300
#define K_   11
#define NCH  4      // d-chunks of 128 rows (was 8 x 64)
#define DCH  128
#define NT   10     // e-tiles of 32 (300 padded to 320)
#define QSTR 328    // Q bf16 LDS row stride (stride%32words==4 -> 2-way bank alias = free)
#define CSTR 132    // epilogue sims row stride (floats, %32==4)

typedef __bf16  bf16x8  __attribute__((ext_vector_type(8)));
typedef float   floatx4 __attribute__((ext_vector_type(4)));

// factorized RBF: kernel k (1..10, mu=0.9..-0.9 step -0.2, sigma=0.1):
//   exp(-50(s-mu_k)^2) = t_k * CK2[k],  t_1 = exp(90s-50s^2), t_{k+1} = t_k*exp(-20s)
__device__ __constant__ float CK2_C[10] =
    {2.576757e-18f, 2.288464e-11f, 3.726653e-06f, 1.110900e-02f, 6.065307e-01f,
     6.065307e-01f, 1.110900e-02f, 3.726653e-06f, 2.288464e-11f, 2.576757e-18f};

__device__ __forceinline__ unsigned int pk2(float x, float y) {
    __hip_bfloat162 h = __float22bfloat162_rn(make_float2(x, y));
    union { __hip_bfloat162 h2; unsigned int u; } c;
    c.h2 = h;
    return c.u;
}

union __align__(16) ShQ {
    unsigned short qs[LQ_ * QSTR];  // 41984 B: K-loop Q (bf16, zero-padded to 320)
    float          cs[LQ_ * CSTR];  // 33792 B: epilogue normalized sims (64 x 128d)
};

// Block = (batch, d-chunk of 128), 512 thr = 8 waves; wave w owns d-rows w*16..+16.
// All 512 blocks resident at once (2/CU, 16 waves/CU) -> no tail round, better
// HBM latency hiding than the old 1024x256 config (12 waves/CU + ragged 4th round).
// Q: staged once per block (4x per batch, was 8x). D: B-fragments straight from
// global (L2-hot via XCD swizzle: all chunks of batch b land on XCD b%8).
__global__ __launch_bounds__(512, 4) void knrm_main(
    const float* __restrict__ Q, const float* __restrict__ D,
    const float* __restrict__ mask_d, float* __restrict__ psum)
{
    const int b = blockIdx.x, ch = blockIdx.y, d0 = ch * DCH;
    const int tid  = threadIdx.x;
    const int lane = tid & 63;
    const int w    = tid >> 6;      // 0..7
    const int quad = lane >> 4;
    const int l15  = lane & 15;

    __shared__ ShQ sh;
    __shared__ float qinv_s[LQ_];
    __shared__ __align__(16) float md_s[DCH];

    // ---- Q staging (fp32 -> bf16, zero-padded e>=300) with fused norms ----
    // 8 threads per q-row, 40 elems each (5 x 8).
    const int qrow = tid >> 3, qpart = tid & 7;
    const float* qp = Q + ((size_t)b * LQ_ + qrow) * E_;
    float ssq = 0.f;
#pragma unroll
    for (int j = 0; j < 5; ++j) {
        int e = qpart * 40 + j * 8;
        float4 v0 = (e     < E_) ? *(const float4*)(qp + e)
                                 : make_float4(0.f, 0.f, 0.f, 0.f);
        float4 v1 = (e + 4 < E_) ? *(const float4*)(qp + e + 4)
                                 : make_float4(0.f, 0.f, 0.f, 0.f);
        ssq += v0.x * v0.x + v0.y * v0.y + v0.z * v0.z + v0.w * v0.w;
        ssq += v1.x * v1.x + v1.y * v1.y + v1.z * v1.z + v1.w * v1.w;
        *(uint4*)&sh.qs[qrow * QSTR + e] =
            make_uint4(pk2(v0.x, v0.y), pk2(v0.z, v0.w),
                       pk2(v1.x, v1.y), pk2(v1.z, v1.w));
    }
    ssq += __shfl_xor(ssq, 1);
    ssq += __shfl_xor(ssq, 2);
    ssq += __shfl_xor(ssq, 4);
    if (qpart == 0) qinv_s[qrow] = 1.0f / fmaxf(sqrtf(ssq), 1e-12f);
    if (tid < DCH) md_s[tid] = mask_d[(size_t)b * LD_ + d0 + tid];
    __syncthreads();   // Qs + qinv + md ready

    // ---- K-loop: D B-frags direct from global + MFMA ----
    // Lane (l15,quad): row d0+w*16+l15, cols t*32+quad*8..+8. Per row the 4
    // quads cover 128 contiguous bytes -> 64-B coalesced segments.
    const float* drow = D + ((size_t)b * LD_ + d0 + w * 16 + l15) * E_;
    const float tm0 = (quad <= 1) ? 1.f : 0.f;            // tile-9 validity
    const float tm1 = (quad == 0) ? 1.f : 0.f;            // (cols >= 300 masked)

    floatx4 acc[4];
    floatx4 zero4 = {0.f, 0.f, 0.f, 0.f};
#pragma unroll
    for (int mt = 0; mt < 4; ++mt) acc[mt] = zero4;
    float ssd = 0.f;

#pragma unroll
    for (int t = 0; t < NT; ++t) {
        const int c0 = t * 32 + quad * 8;
        float4 a, c;
        if (t < NT - 1) {
            a = *(const float4*)(drow + c0);
            c = *(const float4*)(drow + c0 + 4);
        } else {   // tile 9: quad0 fully valid, quad1 half, quads 2-3 invalid
            a = *(const float4*)(drow + (quad <= 1 ? c0 : 0));
            c = *(const float4*)(drow + (quad == 0 ? c0 + 4 : 0));
            a.x *= tm0; a.y *= tm0; a.z *= tm0; a.w *= tm0;
            c.x *= tm1; c.y *= tm1; c.z *= tm1; c.w *= tm1;
        }
        ssd += a.x * a.x + a.y * a.y + a.z * a.z + a.w * a.w;
        ssd += c.x * c.x + c.y * c.y + c.z * c.z + c.w * c.w;

        union { uint4 u; bf16x8 v; } bc;
        bc.u = make_uint4(pk2(a.x, a.y), pk2(a.z, a.w),
                          pk2(c.x, c.y), pk2(c.z, c.w));
        const int ebase = t * 32 + quad * 8;
#pragma unroll
        for (int mt = 0; mt < 4; ++mt) {
            bf16x8 af = *(const bf16x8*)&sh.qs[(mt * 16 + l15) * QSTR + ebase];
            acc[mt] = __builtin_amdgcn_mfma_f32_16x16x32_bf16(af, bc.v, acc[mt], 0, 0, 0);
        }
    }

    // d inv-norm: the 4 quads of same l15 covered disjoint col ranges
    ssd += __shfl_xor(ssd, 16);
    ssd += __shfl_xor(ssd, 32);
    const float dinv = 1.0f / fmaxf(sqrtf(ssd), 1e-12f);

    // ---- epilogue: normalized sims -> LDS (aliases Qs), repartition, pool ----
    __syncthreads();   // all Qs fragment reads done before aliasing as cs
#pragma unroll
    for (int mt = 0; mt < 4; ++mt) {
#pragma unroll
        for (int r = 0; r < 4; ++r) {
            int q = mt * 16 + quad * 4 + r;
            sh.cs[q * CSTR + w * 16 + l15] = acc[mt][r] * qinv_s[q] * dinv;
        }
    }
    __syncthreads();

    // q-row x 16-d slice per thread (8 slices cover the 128 d-cols)
    const int pq = tid >> 3, pd = tid & 7;
    union { float4 v[4]; float f[16]; } sb, mb;
#pragma unroll
    for (int i = 0; i < 4; ++i) {
        sb.v[i] = *(const float4*)&sh.cs[pq * CSTR + pd * 16 + i * 4];
        mb.v[i] = *(const float4*)&md_s[pd * 16 + i * 4];
    }

    float kacc[K_];
#pragma unroll
    for (int k = 0; k < K_; ++k) kacc[k] = 0.f;
#pragma unroll
    for (int j = 0; j < 16; ++j) {
        float s = sb.f[j];
        float m = mb.f[j];
        // kernel 0 (sigma=0.001): exact
        float df0 = s - 1.0f;
        kacc[0] = fmaf(__expf(df0 * df0 * -500000.0f), m, kacc[0]);
        // kernels 1..10: factorized (3 exps total)
        float t1 = __expf(fmaf(-50.0f * s, s, 90.0f * s));  // arg <= 40.5, no ovf
        float r  = __expf(-20.0f * s);
        float t  = t1 * m;
#pragma unroll
        for (int k = 1; k < K_; ++k) {
            kacc[k] = fmaf(t, CK2_C[k - 1], kacc[k]);
            t *= r;
        }
    }
#pragma unroll
    for (int msk = 1; msk <= 4; msk <<= 1)
#pragma unroll
        for (int k = 0; k < K_; ++k) kacc[k] += __shfl_xor(kacc[k], msk);

    if (pd == 0) {
        // layout [b][q][ch][k] -> final kernel reads 44 contiguous floats per q
        const size_t base = (((size_t)b * LQ_ + pq) * NCH + ch) * K_;
#pragma unroll
        for (int k = 0; k < K_; ++k) psum[base + k] = kacc[k];
    }
}

// Combine chunk partials, log-pool, dense + tanh. One wave per batch.
__global__ __launch_bounds__(64) void knrm_final(
    const float* __restrict__ psum, const float* __restrict__ mask_q,
    const float* __restrict__ dw, const float* __restrict__ db,
    float* __restrict__ out)
{
    const int b = blockIdx.x;
    const int q = threadIdx.x;  // 0..63

    const float* pp = psum + ((size_t)b * LQ_ + q) * (NCH * K_);
    union { float4 v[NCH * K_ / 4]; float f[NCH * K_]; } buf;  // 44 floats
#pragma unroll
    for (int i = 0; i < NCH * K_ / 4; ++i)
        buf.v[i] = *(const float4*)(pp + i * 4);

    float t = 0.0f;
#pragma unroll
    for (int k = 0; k < K_; ++k) {
        float p = buf.f[k] + buf.f[K_ + k] + buf.f[2 * K_ + k] + buf.f[3 * K_ + k];
        p = fmaxf(p, 1e-10f);
        t += logf(p) * dw[k];
    }
    t *= 0.01f * mask_q[(size_t)b * LQ_ + q];

#pragma unroll
    for (int m = 32; m >= 1; m >>= 1) t += __shfl_xor(t, m);
    if (q == 0) out[b] = tanhf(t + db[0]);
}

extern "C" void kernel_launch(void* const* d_in, const int* in_sizes, int n_in,
                              void* d_out, int out_size, void* d_ws, size_t ws_size,
                              hipStream_t stream) {
    const float* Q   = (const float*)d_in[0];  // [B, LQ, E]
    const float* D   = (const float*)d_in[1];  // [B, LD, E]
    const float* mq  = (const float*)d_in[2];  // [B, LQ]
    const float* md  = (const float*)d_in[3];  // [B, LD]
    const float* dw  = (const float*)d_in[4];  // [1, K]
    const float* db  = (const float*)d_in[5];  // [1]
    float* out  = (float*)d_out;               // [B, 1]
    float* psum = (float*)d_ws;                // [B][LQ][4][K] = 1.44 MB

    dim3 grid(B_, NCH);                        // same-batch chunks -> same XCD
    knrm_main<<<grid, 512, 0, stream>>>(Q, D, md, psum);
    knrm_final<<<B_, 64, 0, stream>>>(psum, mq, dw, db, out);
}